// Round 7
// baseline (138.769 us; speedup 1.0000x reference)
//
#include <hip/hip_runtime.h>

#define BB 4
#define CCH 64
#define HH 256
#define WW 256
#define PP (HH*WW)     // 65536
#define NS 256         // nh*nw = 16*16

// rel[k] = (k/3 - 1)*16 + (k%3 - 1)  -> {-17,-16,-15,-1,0,1,15,16,17}

// ---------------- Kernel A: superpixel means -> spix[b][s][c] ----------------
__global__ __launch_bounds__(256) void kA_spix_init(const float* __restrict__ x,
                                                    float* __restrict__ spix) {
    int blk = blockIdx.x;          // 4*64*16
    int i = blk & 15;              // superpixel row
    int c = (blk >> 4) & 63;
    int b = blk >> 10;
    int t = threadIdx.x;           // column 0..255
    const float* base = x + ((size_t)(b*CCH + c))*PP + (size_t)i*16*WW + t;
    float s = 0.f;
    #pragma unroll
    for (int r = 0; r < 16; ++r) s += base[(size_t)r*WW];
    #pragma unroll
    for (int off = 8; off; off >>= 1) s += __shfl_down(s, off, 16);
    if ((t & 15) == 0) {
        int j = t >> 4;
        spix[((size_t)b*NS + (i*16 + j))*CCH + c] = s * (1.f/256.f);
    }
}

// ---------------- Kernel F2: fused aff (iter 0) + per-tile partials ----------
// Block = 2 horizontally adjacent tiles (16 rows x 32 cols), 512 threads.
// Loads are 128B-coalesced (2 segments/wave instr). LDS ~57KB -> 2 blocks/CU.
__global__ __launch_bounds__(512, 4) void kF2(const float* __restrict__ x,
                                              const float* __restrict__ spix,
                                              float* __restrict__ partial,
                                              float* __restrict__ wpart) {
    __shared__ float wk[3][4][64];     // 12-label window [dy+1][u+dx+1][c]
    __shared__ float sn[12];
    __shared__ float affL[2][9][268];  // [u][k][tt]
    __shared__ float pixT[2][16][268]; // [u][cl][tt]; cl-stride 268 (2-way banks)
    __shared__ float wsum[8][2][9];
    float (*red)[9][17] = (float(*)[9][17])&pixT[0][0][0];   // 19.6KB alias

    int blk = blockIdx.x;              // B*128
    int pair = blk & 127, b = blk >> 7;
    int ly = pair >> 3, pi = pair & 7;
    int l0 = ly*16 + pi*2;             // left tile label

    int t = threadIdx.x;               // 0..511
    int r = t >> 5;                    // row in tile 0..15
    int c32 = t & 31;                  // col in 32-wide pair
    int u = c32 >> 4;                  // which tile
    int tt = r*16 + (c32 & 15);        // tile-local pixel index
    int lane = t & 63, w = t >> 6;

    // 12-label window: rows {l0-17.., l0-1.., l0+15..}, 4 cols each
    for (int idx = t; idx < 12*64; idx += 512) {
        int j = idx >> 6, c = idx & 63;
        int row = j >> 2, col = j & 3;
        int base = (row == 0) ? -17 : (row == 1) ? -1 : 15;
        int s = l0 + base + col;
        float v = 0.f;
        if (s >= 0 && s < NS) v = spix[((size_t)b*NS + s)*CCH + c];
        wk[row][col][c] = v;
    }
    __syncthreads();
    if (t < 12) {
        int row = t >> 2, col = t & 3;
        float s = 0.f;
        #pragma unroll
        for (int c4 = 0; c4 < 16; ++c4) {
            float4 v = *reinterpret_cast<const float4*>(&wk[row][col][c4*4]);
            s += v.x*v.x + v.y*v.y + v.z*v.z + v.w*v.w;
        }
        sn[t] = s;
    }
    __syncthreads();

    // x loads: gp spans 32 consecutive columns per 32-lane half -> 128B segments
    int gp = (ly*16 + r)*WW + pi*32 + c32;
    const float* px = x + (size_t)b*CCH*PP + gp;

    float xr[64];
    float cross[9];
    #pragma unroll
    for (int k = 0; k < 9; ++k) cross[k] = 0.f;
    float pn = 0.f;
    #pragma unroll
    for (int cc = 0; cc < 16; ++cc) {
        float v0 = px[(size_t)(cc*4+0)*PP];
        float v1 = px[(size_t)(cc*4+1)*PP];
        float v2 = px[(size_t)(cc*4+2)*PP];
        float v3 = px[(size_t)(cc*4+3)*PP];
        xr[cc*4+0] = v0; xr[cc*4+1] = v1; xr[cc*4+2] = v2; xr[cc*4+3] = v3;
        pn += v0*v0 + v1*v1 + v2*v2 + v3*v3;
        #pragma unroll
        for (int k = 0; k < 9; ++k) {
            const float4 s = *reinterpret_cast<const float4*>(&wk[k/3][u + (k%3)][cc*4]);
            cross[k] += s.x*v0 + s.y*v1 + s.z*v2 + s.w*v3;
        }
    }

    float e[9];
    float m = -1e30f;
    #pragma unroll
    for (int k = 0; k < 9; ++k) {
        int rel = (k/3 - 1)*16 + (k % 3) - 1;
        int s = l0 + u + rel;
        bool valid = (s >= 0) && (s < NS);
        float z = -(pn - 2.f*cross[k] + sn[(k/3)*4 + u + (k%3)]);
        e[k] = valid ? z : -3.0e38f;
        if (valid && z > m) m = z;
    }
    float sum = 0.f;
    #pragma unroll
    for (int k = 0; k < 9; ++k) {
        float v = (e[k] > -2.9e38f) ? expf(e[k] - m) : 0.f;
        e[k] = v;
        sum += v;
    }
    float inv = 1.f / sum;
    #pragma unroll
    for (int k = 0; k < 9; ++k) { e[k] *= inv; affL[u][k][tt] = e[k]; }

    // wpart: butterfly over the 32 lanes sharing u (xor bits 0-3 and 5)
    #pragma unroll
    for (int k = 0; k < 9; ++k) {
        float v = e[k];
        v += __shfl_xor(v, 1);  v += __shfl_xor(v, 2);
        v += __shfl_xor(v, 4);  v += __shfl_xor(v, 8);
        v += __shfl_xor(v, 32);
        if ((lane & 15) == 0 && lane < 32) wsum[w][lane >> 4][k] = v;
    }
    __syncthreads();
    if (t < 18) {
        int u2 = t / 9, k = t % 9;
        float s = 0.f;
        #pragma unroll
        for (int ww = 0; ww < 8; ++ww) s += wsum[ww][u2][k];
        wpart[((size_t)b*9 + k)*NS + (l0 + u2)] = s;
    }

    // partial accumulation: 4 chunks of 16 channels, LDS transpose
    int cl = t & 15, g = t >> 4;          // strip g: tile g&1, rows g>>1
    int gu = g & 1, rr = g >> 1;
    #pragma unroll
    for (int ch = 0; ch < 4; ++ch) {
        if (ch) __syncthreads();          // protect red alias from prev chunk
        #pragma unroll
        for (int ci = 0; ci < 16; ++ci) pixT[u][ci][tt] = xr[ch*16 + ci];
        __syncthreads();
        float acc[9];
        #pragma unroll
        for (int k = 0; k < 9; ++k) acc[k] = 0.f;
        #pragma unroll
        for (int i4 = 0; i4 < 4; ++i4) {
            int base = rr*16 + i4*4;
            const float4 v = *reinterpret_cast<const float4*>(&pixT[gu][cl][base]);
            #pragma unroll
            for (int k = 0; k < 9; ++k) {
                const float4 a = *reinterpret_cast<const float4*>(&affL[gu][k][base]);
                acc[k] += a.x*v.x + a.y*v.y + a.z*v.z + a.w*v.w;
            }
        }
        __syncthreads();                  // pixT reads done -> red may alias
        #pragma unroll
        for (int k = 0; k < 9; ++k) red[g][k][cl] = acc[k];
        __syncthreads();
        if (t < 288) {
            int u2 = t / 144, rem = t % 144;
            int k = rem >> 4, c2 = rem & 15;
            float s = 0.f;
            #pragma unroll
            for (int j = 0; j < 16; ++j) s += red[(j << 1) | u2][k][c2];
            partial[(((size_t)b*9 + k)*NS + (l0 + u2))*CCH + ch*16 + c2] = s;
        }
    }
}

// ---------------- Kernel D: gather + divide -> new spix ---------------------
__global__ __launch_bounds__(256) void kD_update(const float* __restrict__ partial,
                                                 const float* __restrict__ wpart,
                                                 float* __restrict__ spix) {
    int gid = blockIdx.x*256 + threadIdx.x;   // 65536
    int c = gid & 63, s = (gid >> 6) & 255, b = gid >> 14;
    float num = 0.f, den = 0.f;
    #pragma unroll
    for (int k = 0; k < 9; ++k) {
        int rel = (k/3 - 1)*16 + (k%3 - 1);
        int l = s - rel;
        if (l >= 0 && l < NS) {
            num += partial[(((size_t)b*9 + k)*NS + l)*CCH + c];
            den += wpart[((size_t)b*9 + k)*NS + l];
        }
    }
    spix[((size_t)b*NS + s)*CCH + c] = num / (den + 1e-16f);
}

// ---------------- Kernel BE: fused final aff + dense output write -----------
__global__ __launch_bounds__(256) void kBE(const float* __restrict__ x,
                                           const float* __restrict__ spix,
                                           float* __restrict__ out,
                                           int out_size) {
    __shared__ float spw[50][68];
    __shared__ float snw[50];
    __shared__ float affL[9][260];
    int blk = blockIdx.x;           // B*H = 1024
    int y = blk & 255;
    int b = blk >> 8;
    int t = threadIdx.x;            // x coordinate
    int ly = y >> 4;
    int base = ly*16 - 17;

    for (int idx = t; idx < 50*CCH; idx += 256) {
        int j = idx >> 6, c = idx & 63;
        int g = base + j;
        float v = 0.f;
        if (g >= 0 && g < NS) v = spix[((size_t)b*NS + g)*CCH + c];
        spw[j][c] = v;
    }
    __syncthreads();
    if (t < 50) {
        float s = 0.f;
        #pragma unroll
        for (int c4 = 0; c4 < 16; ++c4) {
            float4 v = *reinterpret_cast<const float4*>(&spw[t][c4*4]);
            s += v.x*v.x + v.y*v.y + v.z*v.z + v.w*v.w;
        }
        snw[t] = s;
    }
    __syncthreads();

    int p = y*WW + t;
    const float* px = x + (size_t)b*CCH*PP + p;
    int wl = 17 + (t >> 4);
    int nk[9];
    #pragma unroll
    for (int k = 0; k < 9; ++k) nk[k] = wl + (k/3 - 1)*16 + (k%3 - 1);

    float cross[9];
    #pragma unroll
    for (int k = 0; k < 9; ++k) cross[k] = 0.f;
    float pn = 0.f;
    #pragma unroll
    for (int cc = 0; cc < 16; ++cc) {
        float v0 = px[(size_t)(cc*4+0)*PP];
        float v1 = px[(size_t)(cc*4+1)*PP];
        float v2 = px[(size_t)(cc*4+2)*PP];
        float v3 = px[(size_t)(cc*4+3)*PP];
        pn += v0*v0 + v1*v1 + v2*v2 + v3*v3;
        #pragma unroll
        for (int k = 0; k < 9; ++k) {
            const float4 s = *reinterpret_cast<const float4*>(&spw[nk[k]][cc*4]);
            cross[k] += s.x*v0 + s.y*v1 + s.z*v2 + s.w*v3;
        }
    }

    int label = ly*16 + (t >> 4);
    float e[9];
    float m = -1e30f;
    #pragma unroll
    for (int k = 0; k < 9; ++k) {
        int rel = (k/3 - 1)*16 + (k%3 - 1);
        int sidx = label + rel;
        bool valid = (sidx >= 0) && (sidx < NS);
        float z = -(pn - 2.f*cross[k] + snw[nk[k]]);
        e[k] = valid ? z : -3.0e38f;
        if (valid && z > m) m = z;
    }
    float sum = 0.f;
    #pragma unroll
    for (int k = 0; k < 9; ++k) {
        float v = (e[k] > -2.9e38f) ? expf(e[k] - m) : 0.f;
        e[k] = v;
        sum += v;
    }
    float inv = 1.f / sum;
    #pragma unroll
    for (int k = 0; k < 9; ++k) affL[k][t] = e[k] * inv;
    __syncthreads();

    // ---- dense write: wave w writes rows s ≡ w (mod 4), 1 KB per store row
    int w = t >> 6, lane = t & 63;
    int px4 = lane * 4;
    int labelbase = ly*16 + (px4 >> 4);
    float* orow = out + (size_t)b*NS*PP + (size_t)y*WW + px4;
    #pragma unroll 8
    for (int r = 0; r < 64; ++r) {
        int s = w + 4*r;
        int diff = s - labelbase + 17;
        float4 v = make_float4(0.f, 0.f, 0.f, 0.f);
        if ((unsigned)diff <= 34u && (diff & 15) < 3) {
            int k = (diff >> 4)*3 + (diff & 15);
            v = *(const float4*)&affL[k][px4];
        }
        *(float4*)(orow + (size_t)s*PP) = v;
    }
    if (blk == 0 && t == 0) out[out_size - 1] = 256.0f;   // Output 1: ns
}

extern "C" void kernel_launch(void* const* d_in, const int* in_sizes, int n_in,
                              void* d_out, int out_size, void* d_ws, size_t ws_size,
                              hipStream_t stream) {
    (void)in_sizes; (void)n_in; (void)ws_size;
    const float* x = (const float*)d_in[0];
    float* out = (float*)d_out;
    float* ws = (float*)d_ws;

    float* spix    = ws;                            // 65,536 floats
    float* partial = spix + (size_t)BB*NS*CCH;      // 589,824 floats
    float* wpart   = partial + (size_t)BB*9*NS*CCH; // 9,216 floats

    kA_spix_init<<<BB*CCH*16, 256, 0, stream>>>(x, spix);
    kF2<<<BB*128, 512, 0, stream>>>(x, spix, partial, wpart);
    kD_update<<<BB*NS*CCH/256, 256, 0, stream>>>(partial, wpart, spix);
    kBE<<<BB*HH, 256, 0, stream>>>(x, spix, out, out_size);
}